// Round 10
// baseline (180.278 us; speedup 1.0000x reference)
//
#include <hip/hip_runtime.h>
#include <hip/hip_bf16.h>
#include <cstdint>

#define D 128

typedef __attribute__((ext_vector_type(8))) short short8v;
typedef __attribute__((ext_vector_type(4))) float float4v;
typedef __attribute__((ext_vector_type(4))) unsigned int uint4v;

__device__ __forceinline__ float bf2f(unsigned short u) {
    union { unsigned int i; float f; } x; x.i = ((unsigned int)u) << 16; return x.f;
}
__device__ __forceinline__ unsigned short f2bf(float f) {
    union { float f; unsigned int i; } x; x.f = f;
    unsigned int r = x.i + 0x7FFFu + ((x.i >> 16) & 1u);
    return (unsigned short)(r >> 16);
}

// 8 fp32 -> 8 bf16 via v_cvt_pk_bf16_f32 (RNE, 2 elems/instr)
__device__ __forceinline__ short8v cvt8(const float4 a, const float4 b) {
    union { unsigned int w[4]; short8v s; } pk;
    asm("v_cvt_pk_bf16_f32 %0, %1, %2" : "=v"(pk.w[0]) : "v"(a.x), "v"(a.y));
    asm("v_cvt_pk_bf16_f32 %0, %1, %2" : "=v"(pk.w[1]) : "v"(a.z), "v"(a.w));
    asm("v_cvt_pk_bf16_f32 %0, %1, %2" : "=v"(pk.w[2]) : "v"(b.x), "v"(b.y));
    asm("v_cvt_pk_bf16_f32 %0, %1, %2" : "=v"(pk.w[3]) : "v"(b.z), "v"(b.w));
    return pk.s;
}

__device__ __forceinline__ void detect_body(const int* __restrict__ eidx, int nPairs,
                                            int* __restrict__ flag) {
    __shared__ int anyNZ;
    if (threadIdx.x == 0) anyNZ = 0;
    __syncthreads();
    int cnt = nPairs < 2048 ? nPairs : 2048;
    int local = 0;
    for (int i = threadIdx.x; i < cnt; i += 256)
        if (eidx[2 * i + 1] != 0) local = 1;
    if (local) anyNZ = 1;
    __syncthreads();
    if (threadIdx.x == 0) *flag = (anyNZ == 0) ? 1 : 0;
}

// blocks 0..127: W1 (fp32) -> Bc (bf16 [n=256][k=128]); block 128: int64 detect.
__global__ __launch_bounds__(256) void prep(
    const float* __restrict__ W1, unsigned short* __restrict__ Bc,
    const int* __restrict__ eidx, int nPairs, int* __restrict__ flag)
{
    const int b = blockIdx.x;
    if (b < 128) {
        int i = b * 256 + threadIdx.x;
        int n = i >> 7, k = i & 127;
        Bc[i] = f2bf(W1[(size_t)((n < 128) ? k : k + 128) * D + (n & 127)]);
    } else {
        detect_body(eidx, nPairs, flag);
    }
}

// Fused U|V = X @ W1 via bf16 MFMA, swapped operands; reads fp32 X directly
// (no Xb buffer/pass). 64 nodes x 256 cols per block, 4 mt-tiles.
// B force-hoisted (asm pin), fp32 A depth-1 prefetched, cvt via
// v_cvt_pk_bf16_f32 (2 elems/instr), b1 folded into acc init, cvt_pk epilogue.
__global__ __launch_bounds__(256, 3) void uv_fused(
    const float* __restrict__ X, const unsigned short* __restrict__ Bc,
    const float* __restrict__ b1,
    unsigned short* __restrict__ U, unsigned short* __restrict__ V, int nNodes)
{
    const int t = threadIdx.x;
    const int wave = t >> 6;
    const int l = t & 63;
    const int lr = l & 15;          // node lane / B-col lane
    const int lk = l >> 4;          // k-group lane
    const int n0w = wave * 64;      // this wave's output-col base (0..255)

    // hoisted B fragments: lane holds Bc[col = n0w+nt*16+lr][k = ks*32+lk*8+j]
    short8v bf[4][4];
#pragma unroll
    for (int nt = 0; nt < 4; ++nt)
#pragma unroll
        for (int ks = 0; ks < 4; ++ks)
            bf[nt][ks] = *reinterpret_cast<const short8v*>(
                Bc + (size_t)(n0w + nt * 16 + lr) * D + ks * 32 + lk * 8);
#pragma unroll
    for (int nt = 0; nt < 4; ++nt)
#pragma unroll
        for (int ks = 0; ks < 4; ++ks)
            asm volatile("" : "+v"(bf[nt][ks]));

    // bias for this lane's output cols (0 for V-columns); folded into acc init
    float4 bvv[4];
#pragma unroll
    for (int nt = 0; nt < 4; ++nt) {
        if (n0w < 128)
            bvv[nt] = *reinterpret_cast<const float4*>(b1 + n0w + nt * 16 + lk * 4);
        else
            bvv[nt] = make_float4(0.f, 0.f, 0.f, 0.f);
    }

    int row = blockIdx.x * 64 + lr;
    const float* xcol = X + lk * 8;

    // prologue: load + convert tile 0
    short8v aC[4];
    {
        const float* p = xcol + (size_t)min(row, nNodes - 1) * D;
        float4 x0[4], x1[4];
#pragma unroll
        for (int ks = 0; ks < 4; ++ks) {
            x0[ks] = *reinterpret_cast<const float4*>(p + ks * 32);
            x1[ks] = *reinterpret_cast<const float4*>(p + ks * 32 + 4);
        }
#pragma unroll
        for (int ks = 0; ks < 4; ++ks)
            aC[ks] = cvt8(x0[ks], x1[ks]);
    }

#pragma unroll
    for (int mt = 0; mt < 4; ++mt) {
        // issue next tile's fp32 loads (latency hides under MFMAs below)
        float4 y0[4], y1[4];
        if (mt < 3) {
            const float* p = xcol + (size_t)min(row + 16, nNodes - 1) * D;
#pragma unroll
            for (int ks = 0; ks < 4; ++ks) {
                y0[ks] = *reinterpret_cast<const float4*>(p + ks * 32);
                y1[ks] = *reinterpret_cast<const float4*>(p + ks * 32 + 4);
            }
        }
        // D[wcol][node]: lane holds node=lr, wcols n0w + nt*16 + lk*4 + (0..3)
        float4v acc[4];
#pragma unroll
        for (int nt = 0; nt < 4; ++nt) {
            acc[nt] = (float4v){bvv[nt].x, bvv[nt].y, bvv[nt].z, bvv[nt].w};
#pragma unroll
            for (int ks = 0; ks < 4; ++ks)
                acc[nt] = __builtin_amdgcn_mfma_f32_16x16x32_bf16(
                    bf[nt][ks], aC[ks], acc[nt], 0, 0, 0);
        }
        if (row < nNodes) {
            unsigned short* base = (n0w < 128 ? U : V) + (size_t)row * D + (n0w & 127);
#pragma unroll
            for (int nt = 0; nt < 4; ++nt) {
                unsigned int lo, hi;
                asm("v_cvt_pk_bf16_f32 %0, %1, %2"
                    : "=v"(lo) : "v"(acc[nt][0]), "v"(acc[nt][1]));
                asm("v_cvt_pk_bf16_f32 %0, %1, %2"
                    : "=v"(hi) : "v"(acc[nt][2]), "v"(acc[nt][3]));
                uint2 o = make_uint2(lo, hi);
                *reinterpret_cast<uint2*>(base + nt * 16 + lk * 4) = o;
            }
        }
        // convert next tile after this tile's MFMAs
        if (mt < 3) {
#pragma unroll
            for (int ks = 0; ks < 4; ++ks)
                aC[ks] = cvt8(y0[ks], y1[ks]);
        }
        row += 16;
    }
}

// One edge per 16 lanes (8 dims/lane, 16B gathers), 8 edges per group.
// b1 pre-folded into U; softmax-over-2 as sigmoid. (r7/r9-proven, 49 us.)
__global__ __launch_bounds__(256, 4) void edge_attn(
    const int* __restrict__ eidx, const unsigned short* __restrict__ U,
    const unsigned short* __restrict__ V,
    const float* __restrict__ W2, const float* __restrict__ b2,
    const int* __restrict__ i64flag, float* __restrict__ out,
    int nEdges, int nNodes)
{
    const int t = threadIdx.x;
    const int g = t >> 4;
    const int lane = t & 15;
    const int ebase = (blockIdx.x * 16 + g) * 8;
    if (ebase >= nEdges) return;
    const int is64 = *i64flag;
    const bool vec = ((nEdges & 7) == 0);

    float4 w0 = *reinterpret_cast<const float4*>(W2 + lane * 16);
    float4 w1 = *reinterpret_cast<const float4*>(W2 + lane * 16 + 4);
    float4 w2 = *reinterpret_cast<const float4*>(W2 + lane * 16 + 8);
    float4 w3 = *reinterpret_cast<const float4*>(W2 + lane * 16 + 12);
    const float bb0 = b2[0], bb1 = b2[1];

    int si[8], di[8];
    if (vec) {
        if (!is64) {
            int4 a = *reinterpret_cast<const int4*>(eidx + ebase);
            int4 b = *reinterpret_cast<const int4*>(eidx + ebase + 4);
            int4 c = *reinterpret_cast<const int4*>(eidx + (size_t)nEdges + ebase);
            int4 d = *reinterpret_cast<const int4*>(eidx + (size_t)nEdges + ebase + 4);
            si[0] = a.x; si[1] = a.y; si[2] = a.z; si[3] = a.w;
            si[4] = b.x; si[5] = b.y; si[6] = b.z; si[7] = b.w;
            di[0] = c.x; di[1] = c.y; di[2] = c.z; di[3] = c.w;
            di[4] = d.x; di[5] = d.y; di[6] = d.z; di[7] = d.w;
        } else {
#pragma unroll
            for (int q = 0; q < 4; ++q) {
                int4 a = *reinterpret_cast<const int4*>(eidx + 2 * (size_t)ebase + 4 * q);
                si[2 * q] = a.x; si[2 * q + 1] = a.z;
                int4 c = *reinterpret_cast<const int4*>(
                    eidx + 2 * ((size_t)nEdges + ebase) + 4 * q);
                di[2 * q] = c.x; di[2 * q + 1] = c.z;
            }
        }
    } else {
#pragma unroll
        for (int i = 0; i < 8; ++i) {
            int e = ebase + i; if (e >= nEdges) e = nEdges - 1;
            size_t sOff = is64 ? (size_t)2 * e : (size_t)e;
            size_t dOff = is64 ? (size_t)2 * ((size_t)nEdges + e) : (size_t)nEdges + e;
            si[i] = eidx[sOff];
            di[i] = eidx[dOff];
        }
    }
    const unsigned nmax = (unsigned)(nNodes - 1);
    const unsigned lane16 = (unsigned)lane << 4;
    uint4v u[8], v[8];
#pragma unroll
    for (int i = 0; i < 8; ++i) {
        unsigned off = (min((unsigned)si[i], nmax) << 8) + lane16;
        u[i] = *reinterpret_cast<const uint4v*>((const char*)U + off);
    }
#pragma unroll
    for (int i = 0; i < 8; ++i) {
        unsigned off = (min((unsigned)di[i], nmax) << 8) + lane16;
        v[i] = *reinterpret_cast<const uint4v*>((const char*)V + off);
    }
    asm volatile(""
        : "+v"(u[0]), "+v"(u[1]), "+v"(u[2]), "+v"(u[3]),
          "+v"(u[4]), "+v"(u[5]), "+v"(u[6]), "+v"(u[7]),
          "+v"(v[0]), "+v"(v[1]), "+v"(v[2]), "+v"(v[3]),
          "+v"(v[4]), "+v"(v[5]), "+v"(v[6]), "+v"(v[7]));

    const float wc[16] = {w0.x, w0.y, w0.z, w0.w, w1.x, w1.y, w1.z, w1.w,
                          w2.x, w2.y, w2.z, w2.w, w3.x, w3.y, w3.z, w3.w};

#pragma unroll
    for (int i = 0; i < 8; ++i) {
        const unsigned short* up = reinterpret_cast<const unsigned short*>(&u[i]);
        const unsigned short* vp = reinterpret_cast<const unsigned short*>(&v[i]);
        float s0 = 0.f, s1 = 0.f;
#pragma unroll
        for (int j = 0; j < 8; ++j) {
            float h = fmaxf(bf2f(up[j]) + bf2f(vp[j]), 0.f);   // b1 pre-folded into U
            s0 += h * wc[2 * j];
            s1 += h * wc[2 * j + 1];
        }
#pragma unroll
        for (int m = 8; m; m >>= 1) {
            s0 += __shfl_xor(s0, m);
            s1 += __shfl_xor(s1, m);
        }
        if (lane == 0 && ebase + i < nEdges) {
            const int e = ebase + i;
            float dlt = (s1 + bb1) - (s0 + bb0);
            float e1 = __expf(dlt);
            float a0 = 1.f / (1.f + e1);
            out[e] = a0;
            out[(size_t)nEdges + e] = 1.f - a0;
        }
    }
}

__global__ __launch_bounds__(256) void detect_only(
    const int* __restrict__ eidx, int nPairs, int* __restrict__ flag)
{
    detect_body(eidx, nPairs, flag);
}

// Last-resort fallback: compute h directly per edge.
__global__ __launch_bounds__(256) void edge_attn_direct(
    const int* __restrict__ eidx, const float* __restrict__ X,
    const float* __restrict__ W1, const float* __restrict__ b1,
    const float* __restrict__ W2, const float* __restrict__ b2,
    const int* __restrict__ i64flag, float* __restrict__ out,
    int nEdges, int nNodes)
{
    const int t = threadIdx.x;
    const int lane = t & 31;
    const int e = blockIdx.x * 8 + (t >> 5);
    if (e >= nEdges) return;
    const int is64 = i64flag ? *i64flag : 0;
    size_t sOff = is64 ? (size_t)2 * e : (size_t)e;
    size_t dOff = is64 ? (size_t)2 * ((size_t)nEdges + e) : (size_t)nEdges + e;
    int si = min(max(eidx[sOff], 0), nNodes - 1);
    int di = min(max(eidx[dOff], 0), nNodes - 1);

    const int j0 = lane * 4;
    float4 bv = *reinterpret_cast<const float4*>(b1 + j0);
    float a0 = bv.x, a1 = bv.y, a2 = bv.z, a3 = bv.w;
    const float* xs = X + (size_t)si * D;
    const float* xd = X + (size_t)di * D;
    for (int k = 0; k < 128; ++k) {
        float s = xs[k];
        float4 w = *reinterpret_cast<const float4*>(W1 + (size_t)k * D + j0);
        a0 += s * w.x; a1 += s * w.y; a2 += s * w.z; a3 += s * w.w;
        float d = xd[k];
        float4 w2r = *reinterpret_cast<const float4*>(W1 + (size_t)(k + 128) * D + j0);
        a0 += d * w2r.x; a1 += d * w2r.y; a2 += d * w2r.z; a3 += d * w2r.w;
    }
    a0 = fmaxf(a0, 0.f); a1 = fmaxf(a1, 0.f); a2 = fmaxf(a2, 0.f); a3 = fmaxf(a3, 0.f);
    float4 wa = *reinterpret_cast<const float4*>(W2 + j0 * 2);
    float4 wb = *reinterpret_cast<const float4*>(W2 + j0 * 2 + 4);
    float s0 = a0 * wa.x + a1 * wa.z + a2 * wb.x + a3 * wb.z;
    float s1 = a0 * wa.y + a1 * wa.w + a2 * wb.y + a3 * wb.w;
#pragma unroll
    for (int m = 16; m; m >>= 1) {
        s0 += __shfl_xor(s0, m);
        s1 += __shfl_xor(s1, m);
    }
    if (lane == 0) {
        s0 += b2[0]; s1 += b2[1];
        float mx = fmaxf(s0, s1);
        float e0 = __expf(s0 - mx), e1 = __expf(s1 - mx);
        float r = 1.f / (e0 + e1);
        out[e] = e0 * r;
        out[(size_t)nEdges + e] = e1 * r;
    }
}

extern "C" void kernel_launch(void* const* d_in, const int* in_sizes, int n_in,
                              void* d_out, int out_size, void* d_ws, size_t ws_size,
                              hipStream_t stream)
{
    const float* X   = (const float*)d_in[0];
    const int*   eix = (const int*)d_in[1];
    const float* W1  = (const float*)d_in[2];
    const float* b1  = (const float*)d_in[3];
    const float* W2  = (const float*)d_in[4];
    const float* b2  = (const float*)d_in[5];
    float* out = (float*)d_out;

    const int nNodes = in_sizes[0] / D;
    const int nEdges = in_sizes[1] / 2;
    const size_t uvElems = (size_t)nNodes * D;
    const size_t uvBytes = uvElems * sizeof(unsigned short);
    const size_t bcBytes = 256 * D * sizeof(unsigned short);   // 64 KB
    const int nbEdge8 = (nEdges + 127) / 128;

    if (ws_size >= bcBytes + 2 * uvBytes + 16) {
        // Bc | U | V | flag
        unsigned short* Bc = (unsigned short*)d_ws;
        unsigned short* U  = (unsigned short*)((char*)d_ws + bcBytes);
        unsigned short* V  = U + uvElems;
        int* flag = (int*)((char*)d_ws + bcBytes + 2 * uvBytes);
        prep<<<129, 256, 0, stream>>>(W1, Bc, eix, nEdges, flag);
        uv_fused<<<(nNodes + 63) / 64, 256, 0, stream>>>(X, Bc, b1, U, V, nNodes);
        edge_attn<<<nbEdge8, 256, 0, stream>>>(eix, U, V, W2, b2, flag, out, nEdges, nNodes);
    } else {
        int* flag = (ws_size >= 4) ? (int*)d_ws : nullptr;
        if (flag) detect_only<<<1, 256, 0, stream>>>(eix, nEdges, flag);
        const int nbEdge = (nEdges + 7) / 8;
        edge_attn_direct<<<nbEdge, 256, 0, stream>>>(eix, X, W1, b1, W2, b2, flag, out, nEdges, nNodes);
    }
}